// Round 1
// baseline (184.193 us; speedup 1.0000x reference)
//
#include <hip/hip_runtime.h>
#include <math.h>

// Problem constants (fixed by setup_inputs)
#define NPRIM   512
#define TOPK    8
#define PSTRIDE 28          // floats per primitive record (7 x float4)
#define IMG_H   200
#define IMG_W   200
#define NPIX    (IMG_H * IMG_W)

// record layout:
// 0:px 1:py 2:conA 3:conB 4:conC 5:a2x/W 6:a2y/W 7:op_eff
// 8..10: rgb 11: pad 12..19: coeff 20..27: omega (=2*pi*0.125*idx)

__global__ __launch_bounds__(NPRIM) void prep_sort_kernel(
    const float* __restrict__ colors,
    const float* __restrict__ opacities,
    const float* __restrict__ positions,
    const float* __restrict__ scales,
    const float* __restrict__ rotations,
    const float* __restrict__ wcoef,
    const int*   __restrict__ widx,
    const float* __restrict__ view,
    const float* __restrict__ VP,
    float* __restrict__ table,
    int*   __restrict__ order)
{
    const int n = threadIdx.x;
    const float tanx = 0.57735026918962576451f; // tan(30 deg)
    const float fx = IMG_W / (2.0f * tanx);
    const float fy = IMG_H / (2.0f * tanx);

    // quaternion -> rotation matrix
    float qr = rotations[n*4+0], qx = rotations[n*4+1];
    float qy = rotations[n*4+2], qz = rotations[n*4+3];
    float qn = sqrtf(qr*qr + qx*qx + qy*qy + qz*qz) + 1e-8f;
    qr /= qn; qx /= qn; qy /= qn; qz /= qn;
    float R00 = 1.f - 2.f*(qy*qy + qz*qz), R01 = 2.f*(qx*qy - qr*qz), R02 = 2.f*(qx*qz + qr*qy);
    float R10 = 2.f*(qx*qy + qr*qz), R11 = 1.f - 2.f*(qx*qx + qz*qz), R12 = 2.f*(qy*qz - qr*qx);
    float R20 = 2.f*(qx*qz - qr*qy), R21 = 2.f*(qy*qz + qr*qx), R22 = 1.f - 2.f*(qx*qx + qy*qy);

    float s0 = expf(scales[n*3+0]); s0 *= s0;
    float s1 = expf(scales[n*3+1]); s1 *= s1;
    float s2 = expf(scales[n*3+2]); s2 *= s2;

    // Sigma = R diag(s^2) R^T (symmetric)
    float S00 = R00*R00*s0 + R01*R01*s1 + R02*R02*s2;
    float S01 = R00*R10*s0 + R01*R11*s1 + R02*R12*s2;
    float S02 = R00*R20*s0 + R01*R21*s1 + R02*R22*s2;
    float S11 = R10*R10*s0 + R11*R11*s1 + R12*R12*s2;
    float S12 = R10*R20*s0 + R11*R21*s1 + R12*R22*s2;
    float S22 = R20*R20*s0 + R21*R21*s1 + R22*R22*s2;

    float px_ = positions[n*3+0], py_ = positions[n*3+1], pz_ = positions[n*3+2];
    float t0 = view[0]*px_ + view[1]*py_ + view[2]*pz_  + view[3];
    float t1 = view[4]*px_ + view[5]*py_ + view[6]*pz_  + view[7];
    float t2 = view[8]*px_ + view[9]*py_ + view[10]*pz_ + view[11];
    float c0 = VP[0]*px_  + VP[1]*py_  + VP[2]*pz_  + VP[3];
    float c1 = VP[4]*px_  + VP[5]*py_  + VP[6]*pz_  + VP[7];
    float w  = VP[12]*px_ + VP[13]*py_ + VP[14]*pz_ + VP[15];

    float denom = (fabsf(w) > 1e-6f) ? w : 1e-6f;
    float pxs = (c0/denom * 0.5f + 0.5f) * (float)IMG_W;
    float pys = (c1/denom * 0.5f + 0.5f) * (float)IMG_H;

    float depth = t2;
    float tz = fmaxf(depth, 0.1f);
    float invz = 1.f / tz;
    float J00 = fx*invz, J02 = -fx*t0*invz*invz;
    float J11 = fy*invz, J12 = -fy*t1*invz*invz;

    // M = J @ view[:3,:3]
    float M00 = J00*view[0] + J02*view[8];
    float M01 = J00*view[1] + J02*view[9];
    float M02 = J00*view[2] + J02*view[10];
    float M10 = J11*view[4] + J12*view[8];
    float M11 = J11*view[5] + J12*view[9];
    float M12 = J11*view[6] + J12*view[10];

    // cov2d = M Sigma M^T
    float T00 = M00*S00 + M01*S01 + M02*S02;
    float T01 = M00*S01 + M01*S11 + M02*S12;
    float T02 = M00*S02 + M01*S12 + M02*S22;
    float T10 = M10*S00 + M11*S01 + M12*S02;
    float T11 = M10*S01 + M11*S11 + M12*S12;
    float T12 = M10*S02 + M11*S12 + M12*S22;
    float cA = T00*M00 + T01*M01 + T02*M02 + 0.3f;
    float cB = T00*M10 + T01*M11 + T02*M12;
    float cC = T10*M10 + T11*M11 + T12*M12 + 0.3f;
    float det  = fmaxf(cA*cC - cB*cB, 1e-12f);
    float idet = 1.f / det;
    float conA = cC*idet, conB = -cB*idet, conC = cA*idet;

    // wave axis a2 = normalize(M @ R[:,0]) / W
    float a2x = M00*R00 + M01*R10 + M02*R20;
    float a2y = M10*R00 + M11*R10 + M12*R20;
    float an = sqrtf(a2x*a2x + a2y*a2y) + 1e-8f;
    a2x = (a2x/an) * (1.0f/(float)IMG_W);
    a2y = (a2y/an) * (1.0f/(float)IMG_W);

    bool valid = (depth > 0.1f) && (w > 1e-4f);
    float op = valid ? opacities[n] : 0.0f;

    float* e = table + n*PSTRIDE;
    e[0]=pxs; e[1]=pys; e[2]=conA; e[3]=conB; e[4]=conC;
    e[5]=a2x; e[6]=a2y; e[7]=op;
    e[8]=colors[n*3+0]; e[9]=colors[n*3+1]; e[10]=colors[n*3+2]; e[11]=0.f;
#pragma unroll
    for (int k = 0; k < TOPK; ++k) {
        e[12+k] = wcoef[n*TOPK+k];
        e[20+k] = 0.78539816339744830962f * (float)widx[n*TOPK+k]; // 2*pi*(128/1024)
    }

    // ---- bitonic sort by (depth, index) ascending ----
    __shared__ float sd[NPRIM];
    __shared__ int   si[NPRIM];
    sd[n] = depth; si[n] = n;
    __syncthreads();
    for (int k = 2; k <= NPRIM; k <<= 1) {
        for (int j = k >> 1; j > 0; j >>= 1) {
            int l = n ^ j;
            if (l > n) {
                float dn = sd[n], dl = sd[l];
                int   in_ = si[n], il = si[l];
                bool gt = (dn > dl) || (dn == dl && in_ > il);
                bool up = ((n & k) == 0);
                if (gt == up) { sd[n] = dl; sd[l] = dn; si[n] = il; si[l] = in_; }
            }
            __syncthreads();
        }
    }
    order[n] = si[n];
}

__global__ __launch_bounds__(256) void render_kernel(
    const float* __restrict__ table,
    const int*   __restrict__ order,
    const float* __restrict__ bg,
    float* __restrict__ out)
{
    __shared__ float lds[NPRIM * PSTRIDE]; // 57344 B, rows already depth-sorted after staging

    for (int r = threadIdx.x; r < NPRIM; r += 256) {
        int src = order[r];
        const float4* s = (const float4*)(table + src*PSTRIDE);
        float4* d = (float4*)(lds + r*PSTRIDE);
#pragma unroll
        for (int q = 0; q < 7; ++q) d[q] = s[q];
    }
    __syncthreads();

    int p = blockIdx.x * 256 + threadIdx.x;
    int x = p % IMG_W, y = p / IMG_W;
    float gx = (float)x + 0.5f, gy = (float)y + 0.5f;

    float T = 1.f, cr = 0.f, cg = 0.f, cb = 0.f;
    for (int i = 0; i < NPRIM; ++i) {
        const float* e = lds + i*PSTRIDE;
        float dx = e[0] - gx, dy = e[1] - gy;
        float pw = -0.5f*(e[2]*dx*dx + e[4]*dy*dy) - e[3]*dx*dy;
        float G = __expf(fminf(pw, 0.f));
        float t = dx*e[5] + dy*e[6];
        float wave = 0.f;
#pragma unroll
        for (int k = 0; k < TOPK; ++k)
            wave += e[12+k] * __cosf(e[20+k] * t);
        float a = fminf(fmaxf(e[7] * G * wave, 0.f), 0.99f);
        float wgt = a * T;
        cr += e[8]*wgt; cg += e[9]*wgt; cb += e[10]*wgt;
        T *= (1.f - a);
    }

    if (p < NPIX) {
        out[p]          = cr + bg[0]*T;
        out[NPIX + p]   = cg + bg[1]*T;
        out[2*NPIX + p] = cb + bg[2]*T;
    }
}

extern "C" void kernel_launch(void* const* d_in, const int* in_sizes, int n_in,
                              void* d_out, int out_size, void* d_ws, size_t ws_size,
                              hipStream_t stream) {
    const float* colors  = (const float*)d_in[0];
    const float* opac    = (const float*)d_in[1];
    const float* bg      = (const float*)d_in[2];
    const float* pos     = (const float*)d_in[3];
    const float* scales  = (const float*)d_in[4];
    const float* rot     = (const float*)d_in[5];
    const float* wcoef   = (const float*)d_in[6];
    const int*   widx    = (const int*)d_in[7];
    // d_in[8] = cam_position (unused by forward)
    const float* view    = (const float*)d_in[9];
    const float* VP      = (const float*)d_in[10];

    float* table = (float*)d_ws;
    int*   order = (int*)((char*)d_ws + NPRIM * PSTRIDE * sizeof(float));

    hipLaunchKernelGGL(prep_sort_kernel, dim3(1), dim3(NPRIM), 0, stream,
                       colors, opac, pos, scales, rot, wcoef, widx, view, VP,
                       table, order);
    hipLaunchKernelGGL(render_kernel, dim3((NPIX + 255) / 256), dim3(256), 0, stream,
                       table, order, bg, (float*)d_out);
}

// Round 2
// 147.212 us; speedup vs baseline: 1.2512x; 1.2512x over previous
//
#include <hip/hip_runtime.h>
#include <math.h>

// Problem constants (fixed by setup_inputs)
#define NPRIM   512
#define TOPK    8
#define PSTRIDE 28          // floats per primitive record (7 x float4)
#define IMG_H   200
#define IMG_W   200
#define NPIX    (IMG_H * IMG_W)
#define NSEG    8           // depth segments per pixel (= waves per block)
#define SEGSZ   (NPRIM / NSEG)   // 64 prims per segment
#define TILE    64          // pixels per block (one lane each)

// record layout (float4 granularity):
// f4[0]: px py conA conB | f4[1]: conC a2x a2y op | f4[2]: r g b pad
// f4[3..4]: coeff[8]     | f4[5..6]: omega[8]

__global__ __launch_bounds__(NPRIM) void prep_rank_kernel(
    const float* __restrict__ colors,
    const float* __restrict__ opacities,
    const float* __restrict__ positions,
    const float* __restrict__ scales,
    const float* __restrict__ rotations,
    const float* __restrict__ wcoef,
    const int*   __restrict__ widx,
    const float* __restrict__ view,
    const float* __restrict__ VP,
    float* __restrict__ table)
{
    const int n = threadIdx.x;
    const float tanx = 0.57735026918962576451f; // tan(30 deg)
    const float fx = IMG_W / (2.0f * tanx);
    const float fy = IMG_H / (2.0f * tanx);

    // quaternion -> rotation matrix
    float qr = rotations[n*4+0], qx = rotations[n*4+1];
    float qy = rotations[n*4+2], qz = rotations[n*4+3];
    float qn = sqrtf(qr*qr + qx*qx + qy*qy + qz*qz) + 1e-8f;
    qr /= qn; qx /= qn; qy /= qn; qz /= qn;
    float R00 = 1.f - 2.f*(qy*qy + qz*qz), R01 = 2.f*(qx*qy - qr*qz), R02 = 2.f*(qx*qz + qr*qy);
    float R10 = 2.f*(qx*qy + qr*qz), R11 = 1.f - 2.f*(qx*qx + qz*qz), R12 = 2.f*(qy*qz - qr*qx);
    float R20 = 2.f*(qx*qz - qr*qy), R21 = 2.f*(qy*qz + qr*qx), R22 = 1.f - 2.f*(qx*qx + qy*qy);

    float s0 = expf(scales[n*3+0]); s0 *= s0;
    float s1 = expf(scales[n*3+1]); s1 *= s1;
    float s2 = expf(scales[n*3+2]); s2 *= s2;

    // Sigma = R diag(s^2) R^T (symmetric)
    float S00 = R00*R00*s0 + R01*R01*s1 + R02*R02*s2;
    float S01 = R00*R10*s0 + R01*R11*s1 + R02*R12*s2;
    float S02 = R00*R20*s0 + R01*R21*s1 + R02*R22*s2;
    float S11 = R10*R10*s0 + R11*R11*s1 + R12*R12*s2;
    float S12 = R10*R20*s0 + R11*R21*s1 + R12*R22*s2;
    float S22 = R20*R20*s0 + R21*R21*s1 + R22*R22*s2;

    float px_ = positions[n*3+0], py_ = positions[n*3+1], pz_ = positions[n*3+2];
    float t0 = view[0]*px_ + view[1]*py_ + view[2]*pz_  + view[3];
    float t1 = view[4]*px_ + view[5]*py_ + view[6]*pz_  + view[7];
    float t2 = view[8]*px_ + view[9]*py_ + view[10]*pz_ + view[11];
    float c0 = VP[0]*px_  + VP[1]*py_  + VP[2]*pz_  + VP[3];
    float c1 = VP[4]*px_  + VP[5]*py_  + VP[6]*pz_  + VP[7];
    float w  = VP[12]*px_ + VP[13]*py_ + VP[14]*pz_ + VP[15];

    float denom = (fabsf(w) > 1e-6f) ? w : 1e-6f;
    float pxs = (c0/denom * 0.5f + 0.5f) * (float)IMG_W;
    float pys = (c1/denom * 0.5f + 0.5f) * (float)IMG_H;

    float depth = t2;
    float tz = fmaxf(depth, 0.1f);
    float invz = 1.f / tz;
    float J00 = fx*invz, J02 = -fx*t0*invz*invz;
    float J11 = fy*invz, J12 = -fy*t1*invz*invz;

    // M = J @ view[:3,:3]
    float M00 = J00*view[0] + J02*view[8];
    float M01 = J00*view[1] + J02*view[9];
    float M02 = J00*view[2] + J02*view[10];
    float M10 = J11*view[4] + J12*view[8];
    float M11 = J11*view[5] + J12*view[9];
    float M12 = J11*view[6] + J12*view[10];

    // cov2d = M Sigma M^T
    float T00 = M00*S00 + M01*S01 + M02*S02;
    float T01 = M00*S01 + M01*S11 + M02*S12;
    float T02 = M00*S02 + M01*S12 + M02*S22;
    float T10 = M10*S00 + M11*S01 + M12*S02;
    float T11 = M10*S01 + M11*S11 + M12*S12;
    float T12 = M10*S02 + M11*S12 + M12*S22;
    float cA = T00*M00 + T01*M01 + T02*M02 + 0.3f;
    float cB = T00*M10 + T01*M11 + T02*M12;
    float cC = T10*M10 + T11*M11 + T12*M12 + 0.3f;
    float det  = fmaxf(cA*cC - cB*cB, 1e-12f);
    float idet = 1.f / det;
    float conA = cC*idet, conB = -cB*idet, conC = cA*idet;

    // wave axis a2 = normalize(M @ R[:,0]) / W
    float a2x = M00*R00 + M01*R10 + M02*R20;
    float a2y = M10*R00 + M11*R10 + M12*R20;
    float an = sqrtf(a2x*a2x + a2y*a2y) + 1e-8f;
    a2x = (a2x/an) * (1.0f/(float)IMG_W);
    a2y = (a2y/an) * (1.0f/(float)IMG_W);

    bool valid = (depth > 0.1f) && (w > 1e-4f);
    float op = valid ? opacities[n] : 0.0f;

    // ---- rank sort: rank = #{m : (d_m, m) < (d_n, n)}  (matches stable argsort)
    __shared__ float sd[NPRIM];
    sd[n] = depth;
    __syncthreads();
    int rank = 0;
#pragma unroll 4
    for (int m = 0; m < NPRIM; ++m) {
        float dm = sd[m];
        rank += (dm < depth) || (dm == depth && m < n);
    }

    // write record directly into its depth-sorted slot
    float* e = table + rank * PSTRIDE;
    e[0]=pxs; e[1]=pys; e[2]=conA; e[3]=conB; e[4]=conC;
    e[5]=a2x; e[6]=a2y; e[7]=op;
    e[8]=colors[n*3+0]; e[9]=colors[n*3+1]; e[10]=colors[n*3+2]; e[11]=0.f;
#pragma unroll
    for (int k = 0; k < TOPK; ++k) {
        e[12+k] = wcoef[n*TOPK+k];
        e[20+k] = 0.78539816339744830962f * (float)widx[n*TOPK+k]; // 2*pi*(128/1024)
    }
}

__global__ __launch_bounds__(NSEG*64, 4) void render_kernel(
    const float* __restrict__ table,   // depth-sorted records
    const float* __restrict__ bg,
    float* __restrict__ out)
{
    __shared__ float  lds[NPRIM * PSTRIDE];   // 57344 B
    __shared__ float4 part[NSEG][TILE];       //  8192 B  (total 64 KiB)

    const int lane = threadIdx.x & 63;        // pixel within tile
    const int wv   = threadIdx.x >> 6;        // depth segment
    const int p    = blockIdx.x * TILE + lane;

    // each wave stages ITS OWN 64-record segment (no inter-wave barrier needed)
    {
        int row = wv * SEGSZ + lane;
        const float4* s = (const float4*)(table + row * PSTRIDE);
        float4* d = (float4*)(lds + row * PSTRIDE);
#pragma unroll
        for (int q = 0; q < 7; ++q) d[q] = s[q];
    }

    const int x = p % IMG_W, y = p / IMG_W;
    const float gx = (float)x + 0.5f, gy = (float)y + 0.5f;

    float T = 1.f, cr = 0.f, cg = 0.f, cb = 0.f;
    const float* seg = lds + (wv * SEGSZ) * PSTRIDE;
    for (int i = 0; i < SEGSZ; ++i) {
        const float4* e4 = (const float4*)(seg + i * PSTRIDE);
        float4 r0 = e4[0], r1 = e4[1], r2 = e4[2];
        float4 c0 = e4[3], c1 = e4[4], w0 = e4[5], w1 = e4[6];
        float dx = r0.x - gx, dy = r0.y - gy;
        float pw = -0.5f*(r0.z*dx*dx + r1.x*dy*dy) - r0.w*dx*dy;
        float G = __expf(fminf(pw, 0.f));
        float t = dx*r1.y + dy*r1.z;
        float wave = c0.x*__cosf(w0.x*t) + c0.y*__cosf(w0.y*t)
                   + c0.z*__cosf(w0.z*t) + c0.w*__cosf(w0.w*t)
                   + c1.x*__cosf(w1.x*t) + c1.y*__cosf(w1.y*t)
                   + c1.z*__cosf(w1.z*t) + c1.w*__cosf(w1.w*t);
        float a = fminf(fmaxf(r1.w * G * wave, 0.f), 0.99f);
        float wgt = a * T;
        cr += r2.x*wgt; cg += r2.y*wgt; cb += r2.z*wgt;
        T *= (1.f - a);
    }
    part[wv][lane] = make_float4(cr, cg, cb, T);

    __syncthreads();

    // combine the 8 depth segments front-to-back (wave 0 only)
    if (threadIdx.x < TILE) {
        float Ta = 1.f, fr = 0.f, fg = 0.f, fb = 0.f;
#pragma unroll
        for (int s = 0; s < NSEG; ++s) {
            float4 v = part[s][lane];
            fr += Ta * v.x; fg += Ta * v.y; fb += Ta * v.z;
            Ta *= v.w;
        }
        if (p < NPIX) {
            out[p]          = fr + bg[0]*Ta;
            out[NPIX + p]   = fg + bg[1]*Ta;
            out[2*NPIX + p] = fb + bg[2]*Ta;
        }
    }
}

extern "C" void kernel_launch(void* const* d_in, const int* in_sizes, int n_in,
                              void* d_out, int out_size, void* d_ws, size_t ws_size,
                              hipStream_t stream) {
    const float* colors  = (const float*)d_in[0];
    const float* opac    = (const float*)d_in[1];
    const float* bg      = (const float*)d_in[2];
    const float* pos     = (const float*)d_in[3];
    const float* scales  = (const float*)d_in[4];
    const float* rot     = (const float*)d_in[5];
    const float* wcoef   = (const float*)d_in[6];
    const int*   widx    = (const int*)d_in[7];
    // d_in[8] = cam_position (unused by forward)
    const float* view    = (const float*)d_in[9];
    const float* VP      = (const float*)d_in[10];

    float* table = (float*)d_ws;

    hipLaunchKernelGGL(prep_rank_kernel, dim3(1), dim3(NPRIM), 0, stream,
                       colors, opac, pos, scales, rot, wcoef, widx, view, VP,
                       table);
    hipLaunchKernelGGL(render_kernel, dim3(NPIX / TILE), dim3(NSEG*64), 0, stream,
                       table, bg, (float*)d_out);
}

// Round 3
// 119.264 us; speedup vs baseline: 1.5444x; 1.2343x over previous
//
#include <hip/hip_runtime.h>
#include <math.h>

// Problem constants (fixed by setup_inputs)
#define NPRIM   512
#define TOPK    8
#define IMG     200
#define NPIX    (IMG * IMG)
#define NSEG    8                 // depth segments = waves per block
#define SEGSZ   (NPRIM / NSEG)    // 64 prims per wave
#define TILE    64                // 8x8 pixel tile, one pixel per lane
#define TILES_X (IMG / 8)         // 25

// LDS layout:
//   cull[n*8]  : px py conA conB conC a2x a2y op      (unconditional reads)
//   heavy[n*20]: r g b pad coeff[8] omega[8]          (read only when active)
//   aux        : sd[512] during sort, part[8][64] float4 during combine

__global__ __launch_bounds__(512, 4) void fused_kernel(
    const float* __restrict__ colors,
    const float* __restrict__ opacities,
    const float* __restrict__ bg,
    const float* __restrict__ positions,
    const float* __restrict__ scales,
    const float* __restrict__ rotations,
    const float* __restrict__ wcoef,
    const int*   __restrict__ widx,
    const float* __restrict__ view,
    const float* __restrict__ VP,
    float* __restrict__ out)
{
    __shared__ float cull [NPRIM * 8];    // 16384 B
    __shared__ float heavy[NPRIM * 20];   // 40960 B
    __shared__ float auxm [NSEG * TILE * 4]; // 8192 B (sd overlaps part)
    float*  sd   = auxm;
    float4* part = (float4*)auxm;

    // ================= per-primitive preprocess (thread n = prim n) =========
    {
        const int n = threadIdx.x;
        const float tanx = 0.57735026918962576451f; // tan(30 deg)
        const float fx = IMG / (2.0f * tanx);
        const float fy = IMG / (2.0f * tanx);

        float qr = rotations[n*4+0], qx = rotations[n*4+1];
        float qy = rotations[n*4+2], qz = rotations[n*4+3];
        float qn = sqrtf(qr*qr + qx*qx + qy*qy + qz*qz) + 1e-8f;
        qr /= qn; qx /= qn; qy /= qn; qz /= qn;
        float R00 = 1.f - 2.f*(qy*qy + qz*qz), R01 = 2.f*(qx*qy - qr*qz), R02 = 2.f*(qx*qz + qr*qy);
        float R10 = 2.f*(qx*qy + qr*qz), R11 = 1.f - 2.f*(qx*qx + qz*qz), R12 = 2.f*(qy*qz - qr*qx);
        float R20 = 2.f*(qx*qz - qr*qy), R21 = 2.f*(qy*qz + qr*qx), R22 = 1.f - 2.f*(qx*qx + qy*qy);

        float s0 = expf(scales[n*3+0]); s0 *= s0;
        float s1 = expf(scales[n*3+1]); s1 *= s1;
        float s2 = expf(scales[n*3+2]); s2 *= s2;

        float S00 = R00*R00*s0 + R01*R01*s1 + R02*R02*s2;
        float S01 = R00*R10*s0 + R01*R11*s1 + R02*R12*s2;
        float S02 = R00*R20*s0 + R01*R21*s1 + R02*R22*s2;
        float S11 = R10*R10*s0 + R11*R11*s1 + R12*R12*s2;
        float S12 = R10*R20*s0 + R11*R21*s1 + R12*R22*s2;
        float S22 = R20*R20*s0 + R21*R21*s1 + R22*R22*s2;

        float px_ = positions[n*3+0], py_ = positions[n*3+1], pz_ = positions[n*3+2];
        float t0 = view[0]*px_ + view[1]*py_ + view[2]*pz_  + view[3];
        float t1 = view[4]*px_ + view[5]*py_ + view[6]*pz_  + view[7];
        float t2 = view[8]*px_ + view[9]*py_ + view[10]*pz_ + view[11];
        float c0 = VP[0]*px_  + VP[1]*py_  + VP[2]*pz_  + VP[3];
        float c1 = VP[4]*px_  + VP[5]*py_  + VP[6]*pz_  + VP[7];
        float w  = VP[12]*px_ + VP[13]*py_ + VP[14]*pz_ + VP[15];

        float denom = (fabsf(w) > 1e-6f) ? w : 1e-6f;
        float pxs = (c0/denom * 0.5f + 0.5f) * (float)IMG;
        float pys = (c1/denom * 0.5f + 0.5f) * (float)IMG;

        float depth = t2;
        float tz = fmaxf(depth, 0.1f);
        float invz = 1.f / tz;
        float J00 = fx*invz, J02 = -fx*t0*invz*invz;
        float J11 = fy*invz, J12 = -fy*t1*invz*invz;

        float M00 = J00*view[0] + J02*view[8];
        float M01 = J00*view[1] + J02*view[9];
        float M02 = J00*view[2] + J02*view[10];
        float M10 = J11*view[4] + J12*view[8];
        float M11 = J11*view[5] + J12*view[9];
        float M12 = J11*view[6] + J12*view[10];

        float T00 = M00*S00 + M01*S01 + M02*S02;
        float T01 = M00*S01 + M01*S11 + M02*S12;
        float T02 = M00*S02 + M01*S12 + M02*S22;
        float T10 = M10*S00 + M11*S01 + M12*S02;
        float T11 = M10*S01 + M11*S11 + M12*S12;
        float T12 = M10*S02 + M11*S12 + M12*S22;
        float cA = T00*M00 + T01*M01 + T02*M02 + 0.3f;
        float cB = T00*M10 + T01*M11 + T02*M12;
        float cC = T10*M10 + T11*M11 + T12*M12 + 0.3f;
        float det  = fmaxf(cA*cC - cB*cB, 1e-12f);
        float idet = 1.f / det;
        float conA = cC*idet, conB = -cB*idet, conC = cA*idet;

        float a2x = M00*R00 + M01*R10 + M02*R20;
        float a2y = M10*R00 + M11*R10 + M12*R20;
        float an = sqrtf(a2x*a2x + a2y*a2y) + 1e-8f;
        a2x = (a2x/an) * (1.0f/(float)IMG);
        a2y = (a2y/an) * (1.0f/(float)IMG);

        bool valid = (depth > 0.1f) && (w > 1e-4f);
        float op = valid ? opacities[n] : 0.0f;

        // rank = #{m : (d_m, m) < (d_n, n)} — matches stable argsort
        sd[n] = depth;
        __syncthreads();
        int rank = 0;
#pragma unroll 8
        for (int m = 0; m < NPRIM; ++m) {
            float dm = sd[m];
            rank += (dm < depth) || (dm == depth && m < n);
        }

        float* cl = cull + rank*8;
        cl[0]=pxs; cl[1]=pys; cl[2]=conA; cl[3]=conB;
        cl[4]=conC; cl[5]=a2x; cl[6]=a2y; cl[7]=op;
        float* hv = heavy + rank*20;
        hv[0]=colors[n*3+0]; hv[1]=colors[n*3+1]; hv[2]=colors[n*3+2]; hv[3]=0.f;
#pragma unroll
        for (int k = 0; k < TOPK; ++k) {
            hv[4+k]  = wcoef[n*TOPK+k];
            hv[12+k] = 0.78539816339744830962f * (float)widx[n*TOPK+k]; // 2*pi*128/1024
        }
    }
    __syncthreads();   // table complete; sd dead from here (aux reused as part)

    // ================= segmented render: wave wv composites prims [wv*64, wv*64+64)
    const int lane = threadIdx.x & 63;
    const int wv   = threadIdx.x >> 6;
    const int tx   = blockIdx.x % TILES_X, ty = blockIdx.x / TILES_X;
    const int x    = tx*8 + (lane & 7);
    const int y    = ty*8 + (lane >> 3);
    const float gx = (float)x + 0.5f, gy = (float)y + 0.5f;

    const float* cw = cull  + wv * SEGSZ * 8;
    const float* hw = heavy + wv * SEGSZ * 20;

    float T = 1.f, cr = 0.f, cg = 0.f, cb = 0.f;
    for (int i = 0; i < SEGSZ; ++i) {
        float4 q0 = *(const float4*)(cw + i*8);
        float4 q1 = *(const float4*)(cw + i*8 + 4);
        float dx = q0.x - gx, dy = q0.y - gy;
        float pw = -0.5f*(q0.z*dx*dx + q1.x*dy*dy) - q0.w*dx*dy;
        if (__any(pw > -15.0f)) {     // wave-uniform cull: skip ~98% of prims
            const float* h = hw + i*20;
            float4 rgbp = *(const float4*)(h);
            float4 c0 = *(const float4*)(h+4),  c1 = *(const float4*)(h+8);
            float4 w0 = *(const float4*)(h+12), w1 = *(const float4*)(h+16);
            float G = __expf(fminf(pw, 0.f));
            float t = dx*q1.y + dy*q1.z;
            float wave = c0.x*__cosf(w0.x*t) + c0.y*__cosf(w0.y*t)
                       + c0.z*__cosf(w0.z*t) + c0.w*__cosf(w0.w*t)
                       + c1.x*__cosf(w1.x*t) + c1.y*__cosf(w1.y*t)
                       + c1.z*__cosf(w1.z*t) + c1.w*__cosf(w1.w*t);
            float a = fminf(fmaxf(q1.w * G * wave, 0.f), 0.99f);
            float wgt = a * T;
            cr += rgbp.x*wgt; cg += rgbp.y*wgt; cb += rgbp.z*wgt;
            T *= (1.f - a);
        }
    }
    part[wv*TILE + lane] = make_float4(cr, cg, cb, T);

    __syncthreads();

    // combine 8 depth segments front-to-back (wave 0)
    if (threadIdx.x < TILE) {
        float Ta = 1.f, fr = 0.f, fg = 0.f, fb = 0.f;
#pragma unroll
        for (int s = 0; s < NSEG; ++s) {
            float4 v = part[s*TILE + lane];
            fr += Ta * v.x; fg += Ta * v.y; fb += Ta * v.z;
            Ta *= v.w;
        }
        const int p = y*IMG + x;
        out[p]          = fr + bg[0]*Ta;
        out[NPIX + p]   = fg + bg[1]*Ta;
        out[2*NPIX + p] = fb + bg[2]*Ta;
    }
}

extern "C" void kernel_launch(void* const* d_in, const int* in_sizes, int n_in,
                              void* d_out, int out_size, void* d_ws, size_t ws_size,
                              hipStream_t stream) {
    const float* colors  = (const float*)d_in[0];
    const float* opac    = (const float*)d_in[1];
    const float* bg      = (const float*)d_in[2];
    const float* pos     = (const float*)d_in[3];
    const float* scales  = (const float*)d_in[4];
    const float* rot     = (const float*)d_in[5];
    const float* wcoef   = (const float*)d_in[6];
    const int*   widx    = (const int*)d_in[7];
    // d_in[8] = cam_position (unused by forward)
    const float* view    = (const float*)d_in[9];
    const float* VP      = (const float*)d_in[10];

    hipLaunchKernelGGL(fused_kernel, dim3(TILES_X*TILES_X), dim3(512), 0, stream,
                       colors, opac, bg, pos, scales, rot, wcoef, widx, view, VP,
                       (float*)d_out);
}

// Round 4
// 95.013 us; speedup vs baseline: 1.9386x; 1.2552x over previous
//
#include <hip/hip_runtime.h>
#include <math.h>

// Problem constants (fixed by setup_inputs)
#define NPRIM   512
#define TOPK    8
#define PSTRIDE 28               // floats per primitive record (7 x float4)
#define IMG     200
#define NPIX    (IMG * IMG)
#define NSEG    8                // depth segments = waves per block
#define SEGSZ   (NPRIM / NSEG)   // 64 prims per wave
#define TILE    64               // 8x8 pixel tile, one pixel per lane
#define TILES_X (IMG / 8)        // 25

// table record (float4 granularity):
// f4[0]: px py conA conB | f4[1]: conC a2x a2y op | f4[2]: r g b pad
// f4[3..4]: coeff[8]     | f4[5..6]: omega[8]
// bbox[n]: px py rx ry   (rx = sqrt(30*covA_dilated): bbox of the pw>-15 ellipse)

__global__ __launch_bounds__(NPRIM) void prep_kernel(
    const float* __restrict__ colors,
    const float* __restrict__ opacities,
    const float* __restrict__ positions,
    const float* __restrict__ scales,
    const float* __restrict__ rotations,
    const float* __restrict__ wcoef,
    const int*   __restrict__ widx,
    const float* __restrict__ view,
    const float* __restrict__ VP,
    float* __restrict__ table,
    float4* __restrict__ bbox)
{
    const int n = threadIdx.x;
    const float tanx = 0.57735026918962576451f; // tan(30 deg)
    const float fx = IMG / (2.0f * tanx);
    const float fy = IMG / (2.0f * tanx);

    float qr = rotations[n*4+0], qx = rotations[n*4+1];
    float qy = rotations[n*4+2], qz = rotations[n*4+3];
    float qn = sqrtf(qr*qr + qx*qx + qy*qy + qz*qz) + 1e-8f;
    qr /= qn; qx /= qn; qy /= qn; qz /= qn;
    float R00 = 1.f - 2.f*(qy*qy + qz*qz), R01 = 2.f*(qx*qy - qr*qz), R02 = 2.f*(qx*qz + qr*qy);
    float R10 = 2.f*(qx*qy + qr*qz), R11 = 1.f - 2.f*(qx*qx + qz*qz), R12 = 2.f*(qy*qz - qr*qx);
    float R20 = 2.f*(qx*qz - qr*qy), R21 = 2.f*(qy*qz + qr*qx), R22 = 1.f - 2.f*(qx*qx + qy*qy);

    float s0 = expf(scales[n*3+0]); s0 *= s0;
    float s1 = expf(scales[n*3+1]); s1 *= s1;
    float s2 = expf(scales[n*3+2]); s2 *= s2;

    float S00 = R00*R00*s0 + R01*R01*s1 + R02*R02*s2;
    float S01 = R00*R10*s0 + R01*R11*s1 + R02*R12*s2;
    float S02 = R00*R20*s0 + R01*R21*s1 + R02*R22*s2;
    float S11 = R10*R10*s0 + R11*R11*s1 + R12*R12*s2;
    float S12 = R10*R20*s0 + R11*R21*s1 + R12*R22*s2;
    float S22 = R20*R20*s0 + R21*R21*s1 + R22*R22*s2;

    float px_ = positions[n*3+0], py_ = positions[n*3+1], pz_ = positions[n*3+2];
    float t0 = view[0]*px_ + view[1]*py_ + view[2]*pz_  + view[3];
    float t1 = view[4]*px_ + view[5]*py_ + view[6]*pz_  + view[7];
    float t2 = view[8]*px_ + view[9]*py_ + view[10]*pz_ + view[11];
    float c0 = VP[0]*px_  + VP[1]*py_  + VP[2]*pz_  + VP[3];
    float c1 = VP[4]*px_  + VP[5]*py_  + VP[6]*pz_  + VP[7];
    float w  = VP[12]*px_ + VP[13]*py_ + VP[14]*pz_ + VP[15];

    float denom = (fabsf(w) > 1e-6f) ? w : 1e-6f;
    float pxs = (c0/denom * 0.5f + 0.5f) * (float)IMG;
    float pys = (c1/denom * 0.5f + 0.5f) * (float)IMG;

    float depth = t2;
    float tz = fmaxf(depth, 0.1f);
    float invz = 1.f / tz;
    float J00 = fx*invz, J02 = -fx*t0*invz*invz;
    float J11 = fy*invz, J12 = -fy*t1*invz*invz;

    float M00 = J00*view[0] + J02*view[8];
    float M01 = J00*view[1] + J02*view[9];
    float M02 = J00*view[2] + J02*view[10];
    float M10 = J11*view[4] + J12*view[8];
    float M11 = J11*view[5] + J12*view[9];
    float M12 = J11*view[6] + J12*view[10];

    float T00 = M00*S00 + M01*S01 + M02*S02;
    float T01 = M00*S01 + M01*S11 + M02*S12;
    float T02 = M00*S02 + M01*S12 + M02*S22;
    float T10 = M10*S00 + M11*S01 + M12*S02;
    float T11 = M10*S01 + M11*S11 + M12*S12;
    float T12 = M10*S02 + M11*S12 + M12*S22;
    float cA = T00*M00 + T01*M01 + T02*M02 + 0.3f;
    float cB = T00*M10 + T01*M11 + T02*M12;
    float cC = T10*M10 + T11*M11 + T12*M12 + 0.3f;
    float det  = fmaxf(cA*cC - cB*cB, 1e-12f);
    float idet = 1.f / det;
    float conA = cC*idet, conB = -cB*idet, conC = cA*idet;

    float a2x = M00*R00 + M01*R10 + M02*R20;
    float a2y = M10*R00 + M11*R10 + M12*R20;
    float an = sqrtf(a2x*a2x + a2y*a2y) + 1e-8f;
    a2x = (a2x/an) * (1.0f/(float)IMG);
    a2y = (a2y/an) * (1.0f/(float)IMG);

    bool valid = (depth > 0.1f) && (w > 1e-4f);
    float op = valid ? opacities[n] : 0.0f;

    // bbox of the {pw >= -15} ellipse: half-extents sqrt(2*15*cov_dilated_diag)
    float rx = valid ? sqrtf(fmaxf(30.f * cA, 0.f)) : -1e30f;
    float ry = valid ? sqrtf(fmaxf(30.f * cC, 0.f)) : -1e30f;

    // ---- rank sort: rank = #{m : (d_m, m) < (d_n, n)} (matches stable argsort)
    __shared__ float sd[NPRIM];
    sd[n] = depth;
    __syncthreads();
    int rank = 0;
#pragma unroll 8
    for (int m = 0; m < NPRIM; ++m) {
        float dm = sd[m];
        rank += (dm < depth) || (dm == depth && m < n);
    }

    float* e = table + rank * PSTRIDE;
    e[0]=pxs; e[1]=pys; e[2]=conA; e[3]=conB; e[4]=conC;
    e[5]=a2x; e[6]=a2y; e[7]=op;
    e[8]=colors[n*3+0]; e[9]=colors[n*3+1]; e[10]=colors[n*3+2]; e[11]=0.f;
#pragma unroll
    for (int k = 0; k < TOPK; ++k) {
        e[12+k] = wcoef[n*TOPK+k];
        e[20+k] = 0.78539816339744830962f * (float)widx[n*TOPK+k]; // 2*pi*128/1024
    }
    bbox[rank] = make_float4(pxs, pys, rx, ry);
}

__global__ __launch_bounds__(NSEG*64, 4) void render_kernel(
    const float*  __restrict__ table,   // depth-sorted records
    const float4* __restrict__ bbox,    // depth-sorted (px,py,rx,ry)
    const float*  __restrict__ bg,
    float* __restrict__ out)
{
    __shared__ float  lds[NPRIM * PSTRIDE];   // 57344 B
    __shared__ float4 part[NSEG * TILE];      //  8192 B (total 64 KiB)

    const int lane = threadIdx.x & 63;
    const int wv   = threadIdx.x >> 6;
    const int tx   = blockIdx.x % TILES_X, ty = blockIdx.x / TILES_X;
    const int x    = tx*8 + (lane & 7);
    const int y    = ty*8 + (lane >> 3);
    const float gx = (float)x + 0.5f, gy = (float)y + 0.5f;

    // each wave stages ITS OWN 64-record segment (no inter-wave barrier needed)
    {
        const float4* src = (const float4*)table + wv * (SEGSZ * PSTRIDE / 4);
        float4*       dst = (float4*)lds         + wv * (SEGSZ * PSTRIDE / 4);
#pragma unroll
        for (int q = 0; q < 7; ++q) dst[q*64 + lane] = src[q*64 + lane];
    }

    // per-lane box test of one primitive vs this block's 8x8 tile
    const float tcx = (float)(tx*8) + 4.0f, tcy = (float)(ty*8) + 4.0f;
    float4 bb = bbox[wv * SEGSZ + lane];
    bool active = (fabsf(bb.x - tcx) <= bb.z + 3.5f) &&
                  (fabsf(bb.y - tcy) <= bb.w + 3.5f);
    unsigned long long mask = __ballot(active);

    float T = 1.f, cr = 0.f, cg = 0.f, cb = 0.f;
    const float* seg = lds + (wv * SEGSZ) * PSTRIDE;
    while (mask) {
        int j = __ffsll((unsigned long long)mask) - 1;
        mask &= mask - 1;
        const float* h = seg + j * PSTRIDE;
        float4 q0 = *(const float4*)(h);       // broadcast reads, conflict-free
        float4 q1 = *(const float4*)(h + 4);
        float dx = q0.x - gx, dy = q0.y - gy;
        float pw = -0.5f*(q0.z*dx*dx + q1.x*dy*dy) - q0.w*dx*dy;
        if (__any(pw > -15.0f)) {
            float4 q2 = *(const float4*)(h + 8);
            float4 c0 = *(const float4*)(h + 12), c1 = *(const float4*)(h + 16);
            float4 w0 = *(const float4*)(h + 20), w1 = *(const float4*)(h + 24);
            float G = __expf(fminf(pw, 0.f));
            float t = dx*q1.y + dy*q1.z;
            float wave = c0.x*__cosf(w0.x*t) + c0.y*__cosf(w0.y*t)
                       + c0.z*__cosf(w0.z*t) + c0.w*__cosf(w0.w*t)
                       + c1.x*__cosf(w1.x*t) + c1.y*__cosf(w1.y*t)
                       + c1.z*__cosf(w1.z*t) + c1.w*__cosf(w1.w*t);
            float a = fminf(fmaxf(q1.w * G * wave, 0.f), 0.99f);
            float wgt = a * T;
            cr += q2.x*wgt; cg += q2.y*wgt; cb += q2.z*wgt;
            T *= (1.f - a);
        }
    }
    part[wv*TILE + lane] = make_float4(cr, cg, cb, T);

    __syncthreads();

    // combine 8 depth segments front-to-back (wave 0)
    if (threadIdx.x < TILE) {
        float Ta = 1.f, fr = 0.f, fg = 0.f, fb = 0.f;
#pragma unroll
        for (int s = 0; s < NSEG; ++s) {
            float4 v = part[s*TILE + lane];
            fr += Ta * v.x; fg += Ta * v.y; fb += Ta * v.z;
            Ta *= v.w;
        }
        const int p = y*IMG + x;
        out[p]          = fr + bg[0]*Ta;
        out[NPIX + p]   = fg + bg[1]*Ta;
        out[2*NPIX + p] = fb + bg[2]*Ta;
    }
}

extern "C" void kernel_launch(void* const* d_in, const int* in_sizes, int n_in,
                              void* d_out, int out_size, void* d_ws, size_t ws_size,
                              hipStream_t stream) {
    const float* colors  = (const float*)d_in[0];
    const float* opac    = (const float*)d_in[1];
    const float* bg      = (const float*)d_in[2];
    const float* pos     = (const float*)d_in[3];
    const float* scales  = (const float*)d_in[4];
    const float* rot     = (const float*)d_in[5];
    const float* wcoef   = (const float*)d_in[6];
    const int*   widx    = (const int*)d_in[7];
    // d_in[8] = cam_position (unused by forward)
    const float* view    = (const float*)d_in[9];
    const float* VP      = (const float*)d_in[10];

    float*  table = (float*)d_ws;
    float4* bbox  = (float4*)((char*)d_ws + NPRIM * PSTRIDE * sizeof(float));

    hipLaunchKernelGGL(prep_kernel, dim3(1), dim3(NPRIM), 0, stream,
                       colors, opac, pos, scales, rot, wcoef, widx, view, VP,
                       table, bbox);
    hipLaunchKernelGGL(render_kernel, dim3(TILES_X*TILES_X), dim3(NSEG*64), 0, stream,
                       table, bbox, bg, (float*)d_out);
}